// Round 17
// baseline (572.666 us; speedup 1.0000x reference)
//
#include <hip/hip_runtime.h>

typedef unsigned short u16;
typedef unsigned int u32;
typedef __attribute__((ext_vector_type(8))) short short8v;
typedef __attribute__((ext_vector_type(4))) float float4v;

__device__ __forceinline__ float sigm(float x) { return 1.0f / (1.0f + expf(-x)); }
__device__ __forceinline__ u16 f2bf(float f) {
  u32 u = __float_as_uint(f);
  u32 r = (u + 0x7fffu + ((u >> 16) & 1u)) >> 16;
  return (u16)r;
}
__device__ __forceinline__ float bf2f(u16 w) { return __uint_as_float(((u32)w) << 16); }

__global__ void k_zero_f(float* __restrict__ p, int n) {
  int i = blockIdx.x * blockDim.x + threadIdx.x;
  if (i < n) p[i] = 0.0f;
}
__global__ void k_zero_i(int* __restrict__ p, int n) {
  int i = blockIdx.x * blockDim.x + threadIdx.x;
  if (i < n) p[i] = 0;
}

__global__ void k_cnt(const int* __restrict__ dst, int* __restrict__ cnt, int E) {
  int e = blockIdx.x * blockDim.x + threadIdx.x;
  if (e < E) atomicAdd(&cnt[dst[e]], 1);
}

// h[n,f] = relu(sum_k x[n,k] * W_node[k,f] + b_node[f])   [verified r5-r16]
__global__ void k_node(const float* __restrict__ x, const float* __restrict__ Wn,
                       const float* __restrict__ bn, float* __restrict__ h, int N) {
  int tid = blockIdx.x * blockDim.x + threadIdx.x;
  if (tid >= N * 64) return;
  int n = tid >> 6, f = tid & 63;
  float acc = bn[f];
  for (int k = 0; k < 8; ++k) acc += x[(size_t)n * 8 + k] * Wn[k * 64 + f];
  h[tid] = fmaxf(acc, 0.0f);
}

// hmid = relu(relu(ea@Wea+bea)@We1+be1) -> plain bf16   [verified r12-r16]
__global__ void k_edge_mlp(const float* __restrict__ ea_in, const float* __restrict__ Wea,
                           const float* __restrict__ bea, const float* __restrict__ We1,
                           const float* __restrict__ be1, u16* __restrict__ Ahi, int E) {
  int tid = blockIdx.x * blockDim.x + threadIdx.x;
  if (tid >= E * 128) return;
  int e = tid >> 7, t = tid & 127;
  const float* att = ea_in + (size_t)e * 19;
  float ea[12];
  for (int j = 0; j < 12; ++j) {
    float a = bea[j];
    for (int k = 0; k < 19; ++k) a += att[k] * Wea[k * 12 + j];
    ea[j] = fmaxf(a, 0.0f);
  }
  float a = be1[t];
  for (int j = 0; j < 12; ++j) a += ea[j] * We1[j * 128 + t];
  Ahi[tid] = f2bf(fmaxf(a, 0.0f));
}

// Pack W_e2 into MFMA-fragment-ordered bf16   [verified r9-r16]
__global__ void k_pack_b(const float* __restrict__ W2, u16* __restrict__ Bph) {
  int tid = blockIdx.x * blockDim.x + threadIdx.x;
  if (tid >= 128 * 4096) return;
  int j = tid & 7;
  int lane = (tid >> 3) & 63;
  int nt = (tid >> 9) & 3;
  int ks = (tid >> 11) & 3;
  int d = tid >> 13;
  int c = lane & 15, q = lane >> 4;
  int k = ks * 32 + q * 8 + j;
  int n = d * 64 + nt * 16 + c;
  Bph[tid] = f2bf(W2[(size_t)k * 4096 + n]);
}

// Pack GRU weights into MFMA B-fragment order   [verified r16]
__global__ void k_prep_wtf(const float* __restrict__ Wih, const float* __restrict__ Whh,
                           u16* __restrict__ WpI, u16* __restrict__ WpH) {
  int tid = blockIdx.x * blockDim.x + threadIdx.x;
  if (tid >= 2 * 12288) return;
  int w = tid / 12288;
  int r = tid - w * 12288;
  int jj = r & 7;
  int lane = (r >> 3) & 63;
  int t = r >> 9;
  int nt = t % 12, ks = t / 12;
  int c = lane & 15, q = lane >> 4;
  int j = nt * 16 + c;
  int k = ks * 32 + q * 8 + jj;
  const float* W = w ? Whh : Wih;
  u16* Wp = w ? WpH : WpI;
  Wp[r] = f2bf(W[j * 64 + k]);
}

// Fused conv: msg[e,f] = sum_d h[src[e],d] * (Wedge[e,d,f]+b2[d*64+f]);
// agg[dst[e],f] += msg.  Barrier-free d-loop (r15 lesson).
// This round: 64 edges/wave (4 m-tiles) -> per-wave 16KB/d B-read feeds 64 MFMAs,
// halving B L2 traffic vs r14/r16 (the validated bound: time ~ wave-d pairs).
// Block = 128 threads (2 waves) x 128 edges; 4 blocks/CU (8 waves) for latency.
// B in two 8-fragment ks-half buffers (64 VGPRs); b2 folded into the second
// half linearly: msg += hd*acc01; msg += hd*(acc23+b2)  == hd*(acc+b2).
__global__ __launch_bounds__(128, 2) void k_conv_fused(
    const u16* __restrict__ Ahi, const u16* __restrict__ Bph,
    const float* __restrict__ b2, const float* __restrict__ h,
    const int* __restrict__ src, const int* __restrict__ dst,
    float* __restrict__ agg, int E) {
  __shared__ __align__(16) float hs[128 * 36];  // 18.4 KB gathered h slice
  __shared__ __align__(16) float sb2[2048];     // 8 KB b2 slice
  int m0 = blockIdx.x * 128;
  int d0 = blockIdx.y * 32;
  int tid = threadIdx.x;
  int wave = tid >> 6, lane = tid & 63;
  int c = lane & 15, q = lane >> 4;
#pragma unroll
  for (int p = 0; p < 8; ++p) {
    int slot = p * 128 + tid;        // 1024 slots = 128 rows x 8 float4 (32 d-vals)
    int r = slot >> 3, s = slot & 7;
    int ge = m0 + r;
    if (ge >= E) ge = E - 1;
    int sn = src[ge];
    *(float4*)(&hs[r * 36 + s * 4]) = *(const float4*)(h + (size_t)sn * 64 + d0 + s * 4);
  }
#pragma unroll
  for (int p = 0; p < 4; ++p) {
    int slot = p * 128 + tid;        // 512 float4 = 2048 floats of b2 slice
    *(float4*)(&sb2[slot * 4]) = *(const float4*)(b2 + d0 * 64 + slot * 4);
  }
  __syncthreads();
  // A fragments: 4 m-tiles x 4 ks, registers straight from global (r15-validated).
  short8v af[4][4];
#pragma unroll
  for (int mt = 0; mt < 4; ++mt) {
    int gr = m0 + wave * 64 + mt * 16 + c;
    if (gr >= E) gr = E - 1;
#pragma unroll
    for (int ks = 0; ks < 4; ++ks)
      af[mt][ks] = *(const short8v*)(Ahi + (size_t)gr * 128 + ks * 32 + q * 8);
  }
  float msg[4][4][4];
#pragma unroll
  for (int mt = 0; mt < 4; ++mt)
#pragma unroll
    for (int nt = 0; nt < 4; ++nt)
#pragma unroll
      for (int r = 0; r < 4; ++r) msg[mt][nt][r] = 0.0f;

  short8v h0[8], h1[8];
  auto loadHalf = [&](int dd, int hf, short8v* buf) {
    const u16* bp = Bph + (size_t)dd * 8192 + hf * 4096 + lane * 8;
#pragma unroll
    for (int i = 0; i < 8; ++i) buf[i] = *(const short8v*)(bp + i * 512);
  };

  loadHalf(d0, 0, h0);
  for (int d = d0; d < d0 + 32; ++d) {
    int dl = d - d0;
    float hdv[4][4];
#pragma unroll
    for (int mt = 0; mt < 4; ++mt)
#pragma unroll
      for (int r = 0; r < 4; ++r)
        hdv[mt][r] = hs[(wave * 64 + mt * 16 + q * 4 + r) * 36 + dl];
    loadHalf(d, 1, h1);
    // half 0: ks 0,1 -> msg += hd * acc01
#pragma unroll
    for (int mt = 0; mt < 4; ++mt) {
      float4v acc[4];
#pragma unroll
      for (int nt = 0; nt < 4; ++nt) acc[nt] = (float4v){0.f, 0.f, 0.f, 0.f};
#pragma unroll
      for (int kk = 0; kk < 2; ++kk)
#pragma unroll
        for (int nt = 0; nt < 4; ++nt)
          acc[nt] = __builtin_amdgcn_mfma_f32_16x16x32_bf16(af[mt][kk], h0[kk * 4 + nt], acc[nt], 0, 0, 0);
#pragma unroll
      for (int nt = 0; nt < 4; ++nt)
#pragma unroll
        for (int r = 0; r < 4; ++r) msg[mt][nt][r] += hdv[mt][r] * acc[nt][r];
    }
    if (d + 1 < d0 + 32) loadHalf(d + 1, 0, h0);
    // half 1: ks 2,3 -> msg += hd * (acc23 + b2)
#pragma unroll
    for (int mt = 0; mt < 4; ++mt) {
      float4v acc[4];
#pragma unroll
      for (int nt = 0; nt < 4; ++nt) acc[nt] = (float4v){0.f, 0.f, 0.f, 0.f};
#pragma unroll
      for (int kk = 0; kk < 2; ++kk)
#pragma unroll
        for (int nt = 0; nt < 4; ++nt)
          acc[nt] = __builtin_amdgcn_mfma_f32_16x16x32_bf16(af[mt][2 + kk], h1[kk * 4 + nt], acc[nt], 0, 0, 0);
#pragma unroll
      for (int nt = 0; nt < 4; ++nt) {
        float b2v = sb2[dl * 64 + nt * 16 + c];
#pragma unroll
        for (int r = 0; r < 4; ++r) msg[mt][nt][r] += hdv[mt][r] * (acc[nt][r] + b2v);
      }
    }
  }
#pragma unroll
  for (int mt = 0; mt < 4; ++mt) {
#pragma unroll
    for (int r = 0; r < 4; ++r) {
      int e = m0 + wave * 64 + mt * 16 + q * 4 + r;
      if (e < E) {
        int dn = dst[e];
        float* ap = agg + (size_t)dn * 64 + c;
#pragma unroll
        for (int nt = 0; nt < 4; ++nt) atomicAdd(ap + nt * 16, msg[mt][nt][r]);
      }
    }
  }
}

// MFMA GRU   [verified r16]
__global__ __launch_bounds__(256, 2) void k_gru_mfma(
    float* __restrict__ agg, const int* __restrict__ cnt,
    const float* __restrict__ cb, const u16* __restrict__ WpI,
    const u16* __restrict__ WpH, const float* __restrict__ bih,
    const float* __restrict__ bhh, const float* __restrict__ hin,
    float* __restrict__ hout, int N) {
  __shared__ __align__(16) u16 sM[64 * 72];
  __shared__ __align__(16) u16 sH[64 * 72];
  __shared__ __align__(16) float sHf[64 * 68];
  int n0 = blockIdx.x * 64;
  int tid = threadIdx.x;
#pragma unroll
  for (int p = 0; p < 16; ++p) {
    int slot = p * 256 + tid;
    int n = slot >> 6, f = slot & 63;
    int gn = n0 + n;
    bool real = (gn < N);
    if (!real) gn = N - 1;
    float cf = fmaxf((float)cnt[gn], 1.0f);
    float av = agg[(size_t)gn * 64 + f];
    if (real) agg[(size_t)gn * 64 + f] = 0.0f;
    float m = fmaxf(av / cf + cb[f], 0.0f);
    float hv = hin[(size_t)gn * 64 + f];
    sM[n * 72 + f] = f2bf(m);
    sH[n * 72 + f] = f2bf(hv);
    sHf[n * 68 + f] = hv;
  }
  __syncthreads();
  int wave = tid >> 6, lane = tid & 63;
  int c = lane & 15, q = lane >> 4;
  short8v am[2], ah[2];
#pragma unroll
  for (int ks = 0; ks < 2; ++ks) {
    am[ks] = *(const short8v*)(&sM[(wave * 16 + c) * 72 + ks * 32 + q * 8]);
    ah[ks] = *(const short8v*)(&sH[(wave * 16 + c) * 72 + ks * 32 + q * 8]);
  }
  float4v accRZ[8], accN[4], accHN[4];
#pragma unroll
  for (int i = 0; i < 8; ++i) accRZ[i] = (float4v){0.f, 0.f, 0.f, 0.f};
#pragma unroll
  for (int i = 0; i < 4; ++i) {
    accN[i] = (float4v){0.f, 0.f, 0.f, 0.f};
    accHN[i] = (float4v){0.f, 0.f, 0.f, 0.f};
  }
#pragma unroll
  for (int ks = 0; ks < 2; ++ks) {
#pragma unroll
    for (int nt = 0; nt < 8; ++nt) {
      short8v bI = *(const short8v*)(WpI + ((size_t)(ks * 12 + nt) * 64 + lane) * 8);
      short8v bH = *(const short8v*)(WpH + ((size_t)(ks * 12 + nt) * 64 + lane) * 8);
      accRZ[nt] = __builtin_amdgcn_mfma_f32_16x16x32_bf16(am[ks], bI, accRZ[nt], 0, 0, 0);
      accRZ[nt] = __builtin_amdgcn_mfma_f32_16x16x32_bf16(ah[ks], bH, accRZ[nt], 0, 0, 0);
    }
#pragma unroll
    for (int nt = 0; nt < 4; ++nt) {
      short8v bI = *(const short8v*)(WpI + ((size_t)(ks * 12 + 8 + nt) * 64 + lane) * 8);
      short8v bH = *(const short8v*)(WpH + ((size_t)(ks * 12 + 8 + nt) * 64 + lane) * 8);
      accN[nt] = __builtin_amdgcn_mfma_f32_16x16x32_bf16(am[ks], bI, accN[nt], 0, 0, 0);
      accHN[nt] = __builtin_amdgcn_mfma_f32_16x16x32_bf16(ah[ks], bH, accHN[nt], 0, 0, 0);
    }
  }
#pragma unroll
  for (int nt = 0; nt < 4; ++nt) {
    int f = nt * 16 + c;
    float brz_r = bih[f] + bhh[f];
    float brz_z = bih[64 + f] + bhh[64 + f];
    float bin = bih[128 + f];
    float bhn = bhh[128 + f];
#pragma unroll
    for (int r = 0; r < 4; ++r) {
      int nl = wave * 16 + q * 4 + r;
      int gn = n0 + nl;
      float rr = sigm(accRZ[nt][r] + brz_r);
      float zz = sigm(accRZ[nt + 4][r] + brz_z);
      float ng = tanhf(accN[nt][r] + bin + rr * (accHN[nt][r] + bhn));
      float hv = sHf[nl * 68 + f];
      if (gn < N) hout[(size_t)gn * 64 + f] = (1.0f - zz) * ng + zz * hv;
    }
  }
}

// final MLP   [verified r5-r16]
__global__ void k_final(const float* __restrict__ h, const float* __restrict__ ea3,
                        const int* __restrict__ idx3, const float* __restrict__ Wl1,
                        const float* __restrict__ bl1, const float* __restrict__ Wl2,
                        const float* __restrict__ bl2, float* __restrict__ out, int E3) {
  int e = blockIdx.x * blockDim.x + threadIdx.x;
  if (e >= E3) return;
  int a = idx3[e], b = idx3[E3 + e];
  float feat[72];
  for (int t = 0; t < 64; ++t)
    feat[t] = 0.5f * (h[(size_t)a * 64 + t] + h[(size_t)b * 64 + t]);
  for (int j = 0; j < 8; ++j) feat[64 + j] = ea3[(size_t)e * 8 + j];
  float o = bl2[0];
  for (int t = 0; t < 128; ++t) {
    float acc = bl1[t];
    for (int k = 0; k < 72; ++k) acc += feat[k] * Wl1[k * 128 + t];
    o += fmaxf(acc, 0.0f) * Wl2[t];
  }
  out[e] = o;
}

extern "C" void kernel_launch(void* const* d_in, const int* in_sizes, int n_in,
                              void* d_out, int out_size, void* d_ws, size_t ws_size,
                              hipStream_t stream) {
  const float* x          = (const float*)d_in[0];
  const float* edge_attr  = (const float*)d_in[1];
  const float* edge_attr3 = (const float*)d_in[2];
  const int*   edge_index = (const int*)d_in[3];
  const int*   edge_index3= (const int*)d_in[4];
  const float* W_node = (const float*)d_in[5];
  const float* b_node = (const float*)d_in[6];
  const float* W_ea   = (const float*)d_in[7];
  const float* b_ea   = (const float*)d_in[8];
  const float* W_e1   = (const float*)d_in[9];
  const float* b_e1   = (const float*)d_in[10];
  const float* W_e2   = (const float*)d_in[11];
  const float* b_e2   = (const float*)d_in[12];
  const float* conv_bias = (const float*)d_in[13];
  const float* W_ih   = (const float*)d_in[14];
  const float* b_ih   = (const float*)d_in[15];
  const float* W_hh   = (const float*)d_in[16];
  const float* b_hh   = (const float*)d_in[17];
  const float* W_l1   = (const float*)d_in[18];
  const float* b_l1   = (const float*)d_in[19];
  const float* W_l2   = (const float*)d_in[20];
  const float* b_l2   = (const float*)d_in[21];

  int N  = in_sizes[0] / 8;
  int E  = in_sizes[1] / 19;
  int E3 = in_sizes[2] / 8;

  char* p = (char*)d_ws;
  auto carve = [&](size_t bytes) -> void* {
    char* q = p;
    p += (bytes + 255) & ~(size_t)255;
    return (void*)q;
  };
  float* hA   = (float*)carve((size_t)N * 64 * 4);
  float* hB   = (float*)carve((size_t)N * 64 * 4);
  float* agg  = (float*)carve((size_t)N * 64 * 4);
  int*   cnt  = (int*)carve((size_t)N * 4);
  u16*   Ahi  = (u16*)carve((size_t)E * 128 * 2);
  u16*   Bph  = (u16*)carve((size_t)128 * 4096 * 2);
  u16*   WpI  = (u16*)carve(12288 * 2);
  u16*   WpH  = (u16*)carve(12288 * 2);

  const int* src = edge_index;
  const int* dst = edge_index + E;

  k_zero_i<<<(N + 255) / 256, 256, 0, stream>>>(cnt, N);
  k_cnt<<<(E + 255) / 256, 256, 0, stream>>>(dst, cnt, E);
  k_node<<<((size_t)N * 64 + 255) / 256, 256, 0, stream>>>(x, W_node, b_node, hA, N);
  k_edge_mlp<<<((size_t)E * 128 + 255) / 256, 256, 0, stream>>>(edge_attr, W_ea, b_ea,
                                                                W_e1, b_e1, Ahi, E);
  k_pack_b<<<(128 * 4096 + 255) / 256, 256, 0, stream>>>(W_e2, Bph);
  k_prep_wtf<<<(2 * 12288 + 255) / 256, 256, 0, stream>>>(W_ih, W_hh, WpI, WpH);
  k_zero_f<<<((size_t)N * 64 + 255) / 256, 256, 0, stream>>>(agg, N * 64);

  float* hcur = hA;
  float* hnxt = hB;
  dim3 gconv((E + 127) / 128, 2);
  int ngru = (N + 63) / 64;
  for (int it = 0; it < 3; ++it) {
    k_conv_fused<<<gconv, 128, 0, stream>>>(Ahi, Bph, b_e2, hcur, src, dst, agg, E);
    k_gru_mfma<<<ngru, 256, 0, stream>>>(agg, cnt, conv_bias, WpI, WpH,
                                         b_ih, b_hh, hcur, hnxt, N);
    float* tmp = hcur; hcur = hnxt; hnxt = tmp;
  }
  k_final<<<(E3 + 255) / 256, 256, 0, stream>>>(hcur, edge_attr3, edge_index3, W_l1, b_l1,
                                                W_l2, b_l2, (float*)d_out, E3);
}

// Round 18
// 475.590 us; speedup vs baseline: 1.2041x; 1.2041x over previous
//
#include <hip/hip_runtime.h>

typedef unsigned short u16;
typedef unsigned int u32;
typedef __attribute__((ext_vector_type(8))) short short8v;
typedef __attribute__((ext_vector_type(4))) float float4v;

__device__ __forceinline__ float sigm(float x) { return 1.0f / (1.0f + expf(-x)); }
__device__ __forceinline__ u16 f2bf(float f) {
  u32 u = __float_as_uint(f);
  u32 r = (u + 0x7fffu + ((u >> 16) & 1u)) >> 16;
  return (u16)r;
}
__device__ __forceinline__ float bf2f(u16 w) { return __uint_as_float(((u32)w) << 16); }

__global__ void k_zero_f(float* __restrict__ p, int n) {
  int i = blockIdx.x * blockDim.x + threadIdx.x;
  if (i < n) p[i] = 0.0f;
}
__global__ void k_zero_i(int* __restrict__ p, int n) {
  int i = blockIdx.x * blockDim.x + threadIdx.x;
  if (i < n) p[i] = 0;
}

__global__ void k_cnt(const int* __restrict__ dst, int* __restrict__ cnt, int E) {
  int e = blockIdx.x * blockDim.x + threadIdx.x;
  if (e < E) atomicAdd(&cnt[dst[e]], 1);
}

// h[n,f] = relu(sum_k x[n,k] * W_node[k,f] + b_node[f])   [verified r5-r17]
__global__ void k_node(const float* __restrict__ x, const float* __restrict__ Wn,
                       const float* __restrict__ bn, float* __restrict__ h, int N) {
  int tid = blockIdx.x * blockDim.x + threadIdx.x;
  if (tid >= N * 64) return;
  int n = tid >> 6, f = tid & 63;
  float acc = bn[f];
  for (int k = 0; k < 8; ++k) acc += x[(size_t)n * 8 + k] * Wn[k * 64 + f];
  h[tid] = fmaxf(acc, 0.0f);
}

// hmid = relu(relu(ea@Wea+bea)@We1+be1) -> plain bf16.
// Restructured: 2 edges/block, ea computed once into LDS (was 128x redundant).
__global__ __launch_bounds__(256) void k_edge_mlp(
    const float* __restrict__ ea_in, const float* __restrict__ Wea,
    const float* __restrict__ bea, const float* __restrict__ We1,
    const float* __restrict__ be1, u16* __restrict__ Ahi, int E) {
  __shared__ float att[2][19];
  __shared__ float ea[2][12];
  int half = threadIdx.x >> 7;   // 0 or 1
  int t = threadIdx.x & 127;
  int e = blockIdx.x * 2 + half;
  bool real = (e < E);
  int ee = real ? e : E - 1;
  if (t < 19) att[half][t] = ea_in[(size_t)ee * 19 + t];
  __syncthreads();
  if (t < 12) {
    float a = bea[t];
#pragma unroll
    for (int k = 0; k < 19; ++k) a += att[half][k] * Wea[k * 12 + t];
    ea[half][t] = fmaxf(a, 0.0f);
  }
  __syncthreads();
  float a = be1[t];
#pragma unroll
  for (int j = 0; j < 12; ++j) a += ea[half][j] * We1[j * 128 + t];
  if (real) Ahi[(size_t)e * 128 + t] = f2bf(fmaxf(a, 0.0f));
}

// Pack W_e2 into MFMA-fragment-ordered bf16   [verified r9-r17]
__global__ void k_pack_b(const float* __restrict__ W2, u16* __restrict__ Bph) {
  int tid = blockIdx.x * blockDim.x + threadIdx.x;
  if (tid >= 128 * 4096) return;
  int j = tid & 7;
  int lane = (tid >> 3) & 63;
  int nt = (tid >> 9) & 3;
  int ks = (tid >> 11) & 3;
  int d = tid >> 13;
  int c = lane & 15, q = lane >> 4;
  int k = ks * 32 + q * 8 + j;
  int n = d * 64 + nt * 16 + c;
  Bph[tid] = f2bf(W2[(size_t)k * 4096 + n]);
}

// Pack GRU weights into MFMA B-fragment order   [verified r16/r17]
__global__ void k_prep_wtf(const float* __restrict__ Wih, const float* __restrict__ Whh,
                           u16* __restrict__ WpI, u16* __restrict__ WpH) {
  int tid = blockIdx.x * blockDim.x + threadIdx.x;
  if (tid >= 2 * 12288) return;
  int w = tid / 12288;
  int r = tid - w * 12288;
  int jj = r & 7;
  int lane = (r >> 3) & 63;
  int t = r >> 9;
  int nt = t % 12, ks = t / 12;
  int c = lane & 15, q = lane >> 4;
  int j = nt * 16 + c;
  int k = ks * 32 + q * 8 + jj;
  const float* W = w ? Whh : Wih;
  u16* Wp = w ? WpH : WpI;
  Wp[r] = f2bf(W[j * 64 + k]);
}

// Fused conv   [REVERTED to r16 verbatim — 87.7 us/iter verified.
// r17's 64-edges/wave spilled (VGPR cap) + halved prefetch distance -> 110 us.
// r15's LDS-B+barrier/d -> 96.8. Keep: 256 thr, 2 m-tiles/wave, barrier-free.]
__global__ __launch_bounds__(256, 2) void k_conv_fused(
    const u16* __restrict__ Ahi, const u16* __restrict__ Bph,
    const float* __restrict__ b2, const float* __restrict__ h,
    const int* __restrict__ src, const int* __restrict__ dst,
    float* __restrict__ agg, int E) {
  __shared__ __align__(16) u16 sAh[128 * 136];
  __shared__ __align__(16) float hs[128 * 36];
  __shared__ __align__(16) float sb2[2048];
  int m0 = blockIdx.x * 128;
  int d0 = blockIdx.y * 32;
  int tid = threadIdx.x;
#pragma unroll
  for (int p = 0; p < 8; ++p) {
    int slot = p * 256 + tid;
    int r = slot >> 4, s = slot & 15;
    int gr = m0 + r;
    if (gr >= E) gr = E - 1;
    *(uint4*)(&sAh[r * 136 + s * 8]) = *(const uint4*)(Ahi + (size_t)gr * 128 + s * 8);
  }
#pragma unroll
  for (int p = 0; p < 4; ++p) {
    int slot = p * 256 + tid;
    int r = slot >> 3, s = slot & 7;
    int ge = m0 + r;
    if (ge >= E) ge = E - 1;
    int sn = src[ge];
    *(float4*)(&hs[r * 36 + s * 4]) = *(const float4*)(h + (size_t)sn * 64 + d0 + s * 4);
  }
#pragma unroll
  for (int p = 0; p < 2; ++p) {
    int slot = p * 256 + tid;
    *(float4*)(&sb2[slot * 4]) = *(const float4*)(b2 + d0 * 64 + slot * 4);
  }
  __syncthreads();
  int wave = tid >> 6, lane = tid & 63;
  int c = lane & 15, q = lane >> 4;
  float msg[2][4][4];
#pragma unroll
  for (int mt = 0; mt < 2; ++mt)
#pragma unroll
    for (int nt = 0; nt < 4; ++nt)
#pragma unroll
      for (int r = 0; r < 4; ++r) msg[mt][nt][r] = 0.0f;

  short8v bufA[16], bufB[16];
  auto loadB = [&](int dd, short8v* buf) {
    const u16* bp = Bph + (size_t)dd * 8192 + lane * 8;
#pragma unroll
    for (int i = 0; i < 16; ++i) buf[i] = *(const short8v*)(bp + i * 512);
  };
  auto compute = [&](int dd, const short8v* buf) {
    int dl = dd - d0;
#pragma unroll
    for (int mt = 0; mt < 2; ++mt) {
      int arow = wave * 32 + mt * 16 + c;
      float4v acc[4];
#pragma unroll
      for (int nt = 0; nt < 4; ++nt) acc[nt] = (float4v){0.f, 0.f, 0.f, 0.f};
#pragma unroll
      for (int ks = 0; ks < 4; ++ks) {
        short8v ah = *(const short8v*)(&sAh[arow * 136 + ks * 32 + q * 8]);
#pragma unroll
        for (int nt = 0; nt < 4; ++nt)
          acc[nt] = __builtin_amdgcn_mfma_f32_16x16x32_bf16(ah, buf[ks * 4 + nt], acc[nt], 0, 0, 0);
      }
      float hd[4];
#pragma unroll
      for (int r = 0; r < 4; ++r)
        hd[r] = hs[(wave * 32 + mt * 16 + q * 4 + r) * 36 + dl];
#pragma unroll
      for (int nt = 0; nt < 4; ++nt) {
        float b2v = sb2[dl * 64 + nt * 16 + c];
#pragma unroll
        for (int r = 0; r < 4; ++r) msg[mt][nt][r] += hd[r] * (acc[nt][r] + b2v);
      }
    }
  };

  loadB(d0, bufA);
  for (int d = d0; d < d0 + 32; d += 2) {
    loadB(d + 1, bufB);
    compute(d, bufA);
    if (d + 2 < d0 + 32) loadB(d + 2, bufA);
    compute(d + 1, bufB);
  }
#pragma unroll
  for (int mt = 0; mt < 2; ++mt) {
#pragma unroll
    for (int r = 0; r < 4; ++r) {
      int e = m0 + wave * 32 + mt * 16 + q * 4 + r;
      if (e < E) {
        int dn = dst[e];
        float* ap = agg + (size_t)dn * 64 + c;
#pragma unroll
        for (int nt = 0; nt < 4; ++nt) atomicAdd(ap + nt * 16, msg[mt][nt][r]);
      }
    }
  }
}

// MFMA GRU   [verified r16/r17]
__global__ __launch_bounds__(256, 2) void k_gru_mfma(
    float* __restrict__ agg, const int* __restrict__ cnt,
    const float* __restrict__ cb, const u16* __restrict__ WpI,
    const u16* __restrict__ WpH, const float* __restrict__ bih,
    const float* __restrict__ bhh, const float* __restrict__ hin,
    float* __restrict__ hout, int N) {
  __shared__ __align__(16) u16 sM[64 * 72];
  __shared__ __align__(16) u16 sH[64 * 72];
  __shared__ __align__(16) float sHf[64 * 68];
  int n0 = blockIdx.x * 64;
  int tid = threadIdx.x;
#pragma unroll
  for (int p = 0; p < 16; ++p) {
    int slot = p * 256 + tid;
    int n = slot >> 6, f = slot & 63;
    int gn = n0 + n;
    bool real = (gn < N);
    if (!real) gn = N - 1;
    float cf = fmaxf((float)cnt[gn], 1.0f);
    float av = agg[(size_t)gn * 64 + f];
    if (real) agg[(size_t)gn * 64 + f] = 0.0f;
    float m = fmaxf(av / cf + cb[f], 0.0f);
    float hv = hin[(size_t)gn * 64 + f];
    sM[n * 72 + f] = f2bf(m);
    sH[n * 72 + f] = f2bf(hv);
    sHf[n * 68 + f] = hv;
  }
  __syncthreads();
  int wave = tid >> 6, lane = tid & 63;
  int c = lane & 15, q = lane >> 4;
  short8v am[2], ah[2];
#pragma unroll
  for (int ks = 0; ks < 2; ++ks) {
    am[ks] = *(const short8v*)(&sM[(wave * 16 + c) * 72 + ks * 32 + q * 8]);
    ah[ks] = *(const short8v*)(&sH[(wave * 16 + c) * 72 + ks * 32 + q * 8]);
  }
  float4v accRZ[8], accN[4], accHN[4];
#pragma unroll
  for (int i = 0; i < 8; ++i) accRZ[i] = (float4v){0.f, 0.f, 0.f, 0.f};
#pragma unroll
  for (int i = 0; i < 4; ++i) {
    accN[i] = (float4v){0.f, 0.f, 0.f, 0.f};
    accHN[i] = (float4v){0.f, 0.f, 0.f, 0.f};
  }
#pragma unroll
  for (int ks = 0; ks < 2; ++ks) {
#pragma unroll
    for (int nt = 0; nt < 8; ++nt) {
      short8v bI = *(const short8v*)(WpI + ((size_t)(ks * 12 + nt) * 64 + lane) * 8);
      short8v bH = *(const short8v*)(WpH + ((size_t)(ks * 12 + nt) * 64 + lane) * 8);
      accRZ[nt] = __builtin_amdgcn_mfma_f32_16x16x32_bf16(am[ks], bI, accRZ[nt], 0, 0, 0);
      accRZ[nt] = __builtin_amdgcn_mfma_f32_16x16x32_bf16(ah[ks], bH, accRZ[nt], 0, 0, 0);
    }
#pragma unroll
    for (int nt = 0; nt < 4; ++nt) {
      short8v bI = *(const short8v*)(WpI + ((size_t)(ks * 12 + 8 + nt) * 64 + lane) * 8);
      short8v bH = *(const short8v*)(WpH + ((size_t)(ks * 12 + 8 + nt) * 64 + lane) * 8);
      accN[nt] = __builtin_amdgcn_mfma_f32_16x16x32_bf16(am[ks], bI, accN[nt], 0, 0, 0);
      accHN[nt] = __builtin_amdgcn_mfma_f32_16x16x32_bf16(ah[ks], bH, accHN[nt], 0, 0, 0);
    }
  }
#pragma unroll
  for (int nt = 0; nt < 4; ++nt) {
    int f = nt * 16 + c;
    float brz_r = bih[f] + bhh[f];
    float brz_z = bih[64 + f] + bhh[64 + f];
    float bin = bih[128 + f];
    float bhn = bhh[128 + f];
#pragma unroll
    for (int r = 0; r < 4; ++r) {
      int nl = wave * 16 + q * 4 + r;
      int gn = n0 + nl;
      float rr = sigm(accRZ[nt][r] + brz_r);
      float zz = sigm(accRZ[nt + 4][r] + brz_z);
      float ng = tanhf(accN[nt][r] + bin + rr * (accHN[nt][r] + bhn));
      float hv = sHf[nl * 68 + f];
      if (gn < N) hout[(size_t)gn * 64 + f] = (1.0f - zz) * ng + zz * hv;
    }
  }
}

// final MLP: 128-thread block per edge3; feat in LDS; coalesced Wl1 reads;
// wave-shuffle reduction. (r5's serial 1-thread/edge version was latency-bound.)
__global__ __launch_bounds__(128) void k_final(
    const float* __restrict__ h, const float* __restrict__ ea3,
    const int* __restrict__ idx3, const float* __restrict__ Wl1,
    const float* __restrict__ bl1, const float* __restrict__ Wl2,
    const float* __restrict__ bl2, float* __restrict__ out, int E3) {
  __shared__ float feat[72];
  __shared__ float red[2];
  int e = blockIdx.x;
  int t = threadIdx.x;
  int a = idx3[e], b = idx3[E3 + e];
  if (t < 64) feat[t] = 0.5f * (h[(size_t)a * 64 + t] + h[(size_t)b * 64 + t]);
  else if (t < 72) feat[t] = ea3[(size_t)e * 8 + (t - 64)];
  __syncthreads();
  float acc = bl1[t];
#pragma unroll 8
  for (int k = 0; k < 72; ++k) acc += feat[k] * Wl1[k * 128 + t];
  float v = fmaxf(acc, 0.0f) * Wl2[t];
#pragma unroll
  for (int off = 32; off > 0; off >>= 1) v += __shfl_down(v, off);
  if ((t & 63) == 0) red[t >> 6] = v;
  __syncthreads();
  if (t == 0) out[e] = red[0] + red[1] + bl2[0];
}

extern "C" void kernel_launch(void* const* d_in, const int* in_sizes, int n_in,
                              void* d_out, int out_size, void* d_ws, size_t ws_size,
                              hipStream_t stream) {
  const float* x          = (const float*)d_in[0];
  const float* edge_attr  = (const float*)d_in[1];
  const float* edge_attr3 = (const float*)d_in[2];
  const int*   edge_index = (const int*)d_in[3];
  const int*   edge_index3= (const int*)d_in[4];
  const float* W_node = (const float*)d_in[5];
  const float* b_node = (const float*)d_in[6];
  const float* W_ea   = (const float*)d_in[7];
  const float* b_ea   = (const float*)d_in[8];
  const float* W_e1   = (const float*)d_in[9];
  const float* b_e1   = (const float*)d_in[10];
  const float* W_e2   = (const float*)d_in[11];
  const float* b_e2   = (const float*)d_in[12];
  const float* conv_bias = (const float*)d_in[13];
  const float* W_ih   = (const float*)d_in[14];
  const float* b_ih   = (const float*)d_in[15];
  const float* W_hh   = (const float*)d_in[16];
  const float* b_hh   = (const float*)d_in[17];
  const float* W_l1   = (const float*)d_in[18];
  const float* b_l1   = (const float*)d_in[19];
  const float* W_l2   = (const float*)d_in[20];
  const float* b_l2   = (const float*)d_in[21];

  int N  = in_sizes[0] / 8;
  int E  = in_sizes[1] / 19;
  int E3 = in_sizes[2] / 8;

  char* p = (char*)d_ws;
  auto carve = [&](size_t bytes) -> void* {
    char* q = p;
    p += (bytes + 255) & ~(size_t)255;
    return (void*)q;
  };
  float* hA   = (float*)carve((size_t)N * 64 * 4);
  float* hB   = (float*)carve((size_t)N * 64 * 4);
  float* agg  = (float*)carve((size_t)N * 64 * 4);
  int*   cnt  = (int*)carve((size_t)N * 4);
  u16*   Ahi  = (u16*)carve((size_t)E * 128 * 2);
  u16*   Bph  = (u16*)carve((size_t)128 * 4096 * 2);
  u16*   WpI  = (u16*)carve(12288 * 2);
  u16*   WpH  = (u16*)carve(12288 * 2);

  const int* src = edge_index;
  const int* dst = edge_index + E;

  k_zero_i<<<(N + 255) / 256, 256, 0, stream>>>(cnt, N);
  k_cnt<<<(E + 255) / 256, 256, 0, stream>>>(dst, cnt, E);
  k_node<<<((size_t)N * 64 + 255) / 256, 256, 0, stream>>>(x, W_node, b_node, hA, N);
  k_edge_mlp<<<(E + 1) / 2, 256, 0, stream>>>(edge_attr, W_ea, b_ea, W_e1, b_e1, Ahi, E);
  k_pack_b<<<(128 * 4096 + 255) / 256, 256, 0, stream>>>(W_e2, Bph);
  k_prep_wtf<<<(2 * 12288 + 255) / 256, 256, 0, stream>>>(W_ih, W_hh, WpI, WpH);
  k_zero_f<<<((size_t)N * 64 + 255) / 256, 256, 0, stream>>>(agg, N * 64);

  float* hcur = hA;
  float* hnxt = hB;
  dim3 gconv((E + 127) / 128, 2);
  int ngru = (N + 63) / 64;
  for (int it = 0; it < 3; ++it) {
    k_conv_fused<<<gconv, 256, 0, stream>>>(Ahi, Bph, b_e2, hcur, src, dst, agg, E);
    k_gru_mfma<<<ngru, 256, 0, stream>>>(agg, cnt, conv_bias, WpI, WpH,
                                         b_ih, b_hh, hcur, hnxt, N);
    float* tmp = hcur; hcur = hnxt; hnxt = tmp;
  }
  k_final<<<E3, 128, 0, stream>>>(hcur, edge_attr3, edge_index3, W_l1, b_l1,
                                  W_l2, b_l2, (float*)d_out, E3);
}

// Round 19
// 450.305 us; speedup vs baseline: 1.2717x; 1.0562x over previous
//
#include <hip/hip_runtime.h>

typedef unsigned short u16;
typedef unsigned int u32;
typedef __attribute__((ext_vector_type(8))) short short8v;
typedef __attribute__((ext_vector_type(4))) float float4v;

__device__ __forceinline__ float sigm(float x) { return 1.0f / (1.0f + __expf(-x)); }
__device__ __forceinline__ u16 f2bf(float f) {
  u32 u = __float_as_uint(f);
  u32 r = (u + 0x7fffu + ((u >> 16) & 1u)) >> 16;
  return (u16)r;
}
__device__ __forceinline__ float bf2f(u16 w) { return __uint_as_float(((u32)w) << 16); }

__global__ void k_zero_f(float* __restrict__ p, int n) {
  int i = blockIdx.x * blockDim.x + threadIdx.x;
  if (i < n) p[i] = 0.0f;
}
__global__ void k_zero_i(int* __restrict__ p, int n) {
  int i = blockIdx.x * blockDim.x + threadIdx.x;
  if (i < n) p[i] = 0;
}

__global__ void k_cnt(const int* __restrict__ dst, int* __restrict__ cnt, int E) {
  int e = blockIdx.x * blockDim.x + threadIdx.x;
  if (e < E) atomicAdd(&cnt[dst[e]], 1);
}

// h[n,f] = relu(sum_k x[n,k] * W_node[k,f] + b_node[f])   [verified r5-r18]
__global__ void k_node(const float* __restrict__ x, const float* __restrict__ Wn,
                       const float* __restrict__ bn, float* __restrict__ h, int N) {
  int tid = blockIdx.x * blockDim.x + threadIdx.x;
  if (tid >= N * 64) return;
  int n = tid >> 6, f = tid & 63;
  float acc = bn[f];
  for (int k = 0; k < 8; ++k) acc += x[(size_t)n * 8 + k] * Wn[k * 64 + f];
  h[tid] = fmaxf(acc, 0.0f);
}

// hmid -> plain bf16; 2 edges/block, ea computed once in LDS   [verified r18]
__global__ __launch_bounds__(256) void k_edge_mlp(
    const float* __restrict__ ea_in, const float* __restrict__ Wea,
    const float* __restrict__ bea, const float* __restrict__ We1,
    const float* __restrict__ be1, u16* __restrict__ Ahi, int E) {
  __shared__ float att[2][19];
  __shared__ float ea[2][12];
  int half = threadIdx.x >> 7;
  int t = threadIdx.x & 127;
  int e = blockIdx.x * 2 + half;
  bool real = (e < E);
  int ee = real ? e : E - 1;
  if (t < 19) att[half][t] = ea_in[(size_t)ee * 19 + t];
  __syncthreads();
  if (t < 12) {
    float a = bea[t];
#pragma unroll
    for (int k = 0; k < 19; ++k) a += att[half][k] * Wea[k * 12 + t];
    ea[half][t] = fmaxf(a, 0.0f);
  }
  __syncthreads();
  float a = be1[t];
#pragma unroll
  for (int j = 0; j < 12; ++j) a += ea[half][j] * We1[j * 128 + t];
  if (real) Ahi[(size_t)e * 128 + t] = f2bf(fmaxf(a, 0.0f));
}

// Pack W_e2 into MFMA-fragment-ordered bf16   [verified r9-r18]
__global__ void k_pack_b(const float* __restrict__ W2, u16* __restrict__ Bph) {
  int tid = blockIdx.x * blockDim.x + threadIdx.x;
  if (tid >= 128 * 4096) return;
  int j = tid & 7;
  int lane = (tid >> 3) & 63;
  int nt = (tid >> 9) & 3;
  int ks = (tid >> 11) & 3;
  int d = tid >> 13;
  int c = lane & 15, q = lane >> 4;
  int k = ks * 32 + q * 8 + j;
  int n = d * 64 + nt * 16 + c;
  Bph[tid] = f2bf(W2[(size_t)k * 4096 + n]);
}

// Pack GRU weights into MFMA B-fragment order   [verified r16-r18]
__global__ void k_prep_wtf(const float* __restrict__ Wih, const float* __restrict__ Whh,
                           u16* __restrict__ WpI, u16* __restrict__ WpH) {
  int tid = blockIdx.x * blockDim.x + threadIdx.x;
  if (tid >= 2 * 12288) return;
  int w = tid / 12288;
  int r = tid - w * 12288;
  int jj = r & 7;
  int lane = (r >> 3) & 63;
  int t = r >> 9;
  int nt = t % 12, ks = t / 12;
  int c = lane & 15, q = lane >> 4;
  int j = nt * 16 + c;
  int k = ks * 32 + q * 8 + jj;
  const float* W = w ? Whh : Wih;
  u16* Wp = w ? WpH : WpI;
  Wp[r] = f2bf(W[j * 64 + k]);
}

// Pack W_l1 (72x128, zero-padded K to 96) into MFMA B-fragment order:
// Wp1[((ks*8+nt)*64 + lane)*8 + j] = bf16(Wl1[k*128+n]), k=ks*32+q*8+j (0 if k>=72),
// n = nt*16 + c.  ks in 0..2, nt in 0..7.
__global__ void k_prep_wl1(const float* __restrict__ Wl1, u16* __restrict__ Wp1) {
  int tid = blockIdx.x * blockDim.x + threadIdx.x;
  if (tid >= 3 * 8 * 64 * 8) return;
  int j = tid & 7;
  int lane = (tid >> 3) & 63;
  int nt = (tid >> 9) & 7;
  int ks = tid >> 12;
  int c = lane & 15, q = lane >> 4;
  int k = ks * 32 + q * 8 + j;
  int n = nt * 16 + c;
  Wp1[tid] = f2bf((k < 72) ? Wl1[k * 128 + n] : 0.0f);
}

// Fused conv   [verified r14/r16/r18: 87.7 us/iter. Keep: 256 thr, 2 m-tiles/wave,
// barrier-free d-loop, B reg-double-buffered. r12/r15/r17 variants all regressed.]
__global__ __launch_bounds__(256, 2) void k_conv_fused(
    const u16* __restrict__ Ahi, const u16* __restrict__ Bph,
    const float* __restrict__ b2, const float* __restrict__ h,
    const int* __restrict__ src, const int* __restrict__ dst,
    float* __restrict__ agg, int E) {
  __shared__ __align__(16) u16 sAh[128 * 136];
  __shared__ __align__(16) float hs[128 * 36];
  __shared__ __align__(16) float sb2[2048];
  int m0 = blockIdx.x * 128;
  int d0 = blockIdx.y * 32;
  int tid = threadIdx.x;
#pragma unroll
  for (int p = 0; p < 8; ++p) {
    int slot = p * 256 + tid;
    int r = slot >> 4, s = slot & 15;
    int gr = m0 + r;
    if (gr >= E) gr = E - 1;
    *(uint4*)(&sAh[r * 136 + s * 8]) = *(const uint4*)(Ahi + (size_t)gr * 128 + s * 8);
  }
#pragma unroll
  for (int p = 0; p < 4; ++p) {
    int slot = p * 256 + tid;
    int r = slot >> 3, s = slot & 7;
    int ge = m0 + r;
    if (ge >= E) ge = E - 1;
    int sn = src[ge];
    *(float4*)(&hs[r * 36 + s * 4]) = *(const float4*)(h + (size_t)sn * 64 + d0 + s * 4);
  }
#pragma unroll
  for (int p = 0; p < 2; ++p) {
    int slot = p * 256 + tid;
    *(float4*)(&sb2[slot * 4]) = *(const float4*)(b2 + d0 * 64 + slot * 4);
  }
  __syncthreads();
  int wave = tid >> 6, lane = tid & 63;
  int c = lane & 15, q = lane >> 4;
  float msg[2][4][4];
#pragma unroll
  for (int mt = 0; mt < 2; ++mt)
#pragma unroll
    for (int nt = 0; nt < 4; ++nt)
#pragma unroll
      for (int r = 0; r < 4; ++r) msg[mt][nt][r] = 0.0f;

  short8v bufA[16], bufB[16];
  auto loadB = [&](int dd, short8v* buf) {
    const u16* bp = Bph + (size_t)dd * 8192 + lane * 8;
#pragma unroll
    for (int i = 0; i < 16; ++i) buf[i] = *(const short8v*)(bp + i * 512);
  };
  auto compute = [&](int dd, const short8v* buf) {
    int dl = dd - d0;
#pragma unroll
    for (int mt = 0; mt < 2; ++mt) {
      int arow = wave * 32 + mt * 16 + c;
      float4v acc[4];
#pragma unroll
      for (int nt = 0; nt < 4; ++nt) acc[nt] = (float4v){0.f, 0.f, 0.f, 0.f};
#pragma unroll
      for (int ks = 0; ks < 4; ++ks) {
        short8v ah = *(const short8v*)(&sAh[arow * 136 + ks * 32 + q * 8]);
#pragma unroll
        for (int nt = 0; nt < 4; ++nt)
          acc[nt] = __builtin_amdgcn_mfma_f32_16x16x32_bf16(ah, buf[ks * 4 + nt], acc[nt], 0, 0, 0);
      }
      float hd[4];
#pragma unroll
      for (int r = 0; r < 4; ++r)
        hd[r] = hs[(wave * 32 + mt * 16 + q * 4 + r) * 36 + dl];
#pragma unroll
      for (int nt = 0; nt < 4; ++nt) {
        float b2v = sb2[dl * 64 + nt * 16 + c];
#pragma unroll
        for (int r = 0; r < 4; ++r) msg[mt][nt][r] += hd[r] * (acc[nt][r] + b2v);
      }
    }
  };

  loadB(d0, bufA);
  for (int d = d0; d < d0 + 32; d += 2) {
    loadB(d + 1, bufB);
    compute(d, bufA);
    if (d + 2 < d0 + 32) loadB(d + 2, bufA);
    compute(d + 1, bufB);
  }
#pragma unroll
  for (int mt = 0; mt < 2; ++mt) {
#pragma unroll
    for (int r = 0; r < 4; ++r) {
      int e = m0 + wave * 32 + mt * 16 + q * 4 + r;
      if (e < E) {
        int dn = dst[e];
        float* ap = agg + (size_t)dn * 64 + c;
#pragma unroll
        for (int nt = 0; nt < 4; ++nt) atomicAdd(ap + nt * 16, msg[mt][nt][r]);
      }
    }
  }
}

// MFMA GRU   [verified r16-r18; sigm now uses __expf (saturation-safe)]
__global__ __launch_bounds__(256, 2) void k_gru_mfma(
    float* __restrict__ agg, const int* __restrict__ cnt,
    const float* __restrict__ cb, const u16* __restrict__ WpI,
    const u16* __restrict__ WpH, const float* __restrict__ bih,
    const float* __restrict__ bhh, const float* __restrict__ hin,
    float* __restrict__ hout, int N) {
  __shared__ __align__(16) u16 sM[64 * 72];
  __shared__ __align__(16) u16 sH[64 * 72];
  __shared__ __align__(16) float sHf[64 * 68];
  int n0 = blockIdx.x * 64;
  int tid = threadIdx.x;
#pragma unroll
  for (int p = 0; p < 16; ++p) {
    int slot = p * 256 + tid;
    int n = slot >> 6, f = slot & 63;
    int gn = n0 + n;
    bool real = (gn < N);
    if (!real) gn = N - 1;
    float cf = fmaxf((float)cnt[gn], 1.0f);
    float av = agg[(size_t)gn * 64 + f];
    if (real) agg[(size_t)gn * 64 + f] = 0.0f;
    float m = fmaxf(av / cf + cb[f], 0.0f);
    float hv = hin[(size_t)gn * 64 + f];
    sM[n * 72 + f] = f2bf(m);
    sH[n * 72 + f] = f2bf(hv);
    sHf[n * 68 + f] = hv;
  }
  __syncthreads();
  int wave = tid >> 6, lane = tid & 63;
  int c = lane & 15, q = lane >> 4;
  short8v am[2], ah[2];
#pragma unroll
  for (int ks = 0; ks < 2; ++ks) {
    am[ks] = *(const short8v*)(&sM[(wave * 16 + c) * 72 + ks * 32 + q * 8]);
    ah[ks] = *(const short8v*)(&sH[(wave * 16 + c) * 72 + ks * 32 + q * 8]);
  }
  float4v accRZ[8], accN[4], accHN[4];
#pragma unroll
  for (int i = 0; i < 8; ++i) accRZ[i] = (float4v){0.f, 0.f, 0.f, 0.f};
#pragma unroll
  for (int i = 0; i < 4; ++i) {
    accN[i] = (float4v){0.f, 0.f, 0.f, 0.f};
    accHN[i] = (float4v){0.f, 0.f, 0.f, 0.f};
  }
#pragma unroll
  for (int ks = 0; ks < 2; ++ks) {
#pragma unroll
    for (int nt = 0; nt < 8; ++nt) {
      short8v bI = *(const short8v*)(WpI + ((size_t)(ks * 12 + nt) * 64 + lane) * 8);
      short8v bH = *(const short8v*)(WpH + ((size_t)(ks * 12 + nt) * 64 + lane) * 8);
      accRZ[nt] = __builtin_amdgcn_mfma_f32_16x16x32_bf16(am[ks], bI, accRZ[nt], 0, 0, 0);
      accRZ[nt] = __builtin_amdgcn_mfma_f32_16x16x32_bf16(ah[ks], bH, accRZ[nt], 0, 0, 0);
    }
#pragma unroll
    for (int nt = 0; nt < 4; ++nt) {
      short8v bI = *(const short8v*)(WpI + ((size_t)(ks * 12 + 8 + nt) * 64 + lane) * 8);
      short8v bH = *(const short8v*)(WpH + ((size_t)(ks * 12 + 8 + nt) * 64 + lane) * 8);
      accN[nt] = __builtin_amdgcn_mfma_f32_16x16x32_bf16(am[ks], bI, accN[nt], 0, 0, 0);
      accHN[nt] = __builtin_amdgcn_mfma_f32_16x16x32_bf16(ah[ks], bH, accHN[nt], 0, 0, 0);
    }
  }
#pragma unroll
  for (int nt = 0; nt < 4; ++nt) {
    int f = nt * 16 + c;
    float brz_r = bih[f] + bhh[f];
    float brz_z = bih[64 + f] + bhh[64 + f];
    float bin = bih[128 + f];
    float bhn = bhh[128 + f];
#pragma unroll
    for (int r = 0; r < 4; ++r) {
      int nl = wave * 16 + q * 4 + r;
      int gn = n0 + nl;
      float rr = sigm(accRZ[nt][r] + brz_r);
      float zz = sigm(accRZ[nt + 4][r] + brz_z);
      float ng = tanhf(accN[nt][r] + bin + rr * (accHN[nt][r] + bhn));
      float hv = sHf[nl * 68 + f];
      if (gn < N) hout[(size_t)gn * 64 + f] = (1.0f - zz) * ng + zz * hv;
    }
  }
}

// MFMA final MLP: 64 edges/block. feat[64][96] bf16 in LDS (h-pair, ea3, zero pad);
// Wl1 pre-packed fragments (L2-hot, 24 KB); relu+Wl2 stage folded into epilogue
// via 16-lane xor-shuffle reduction over D columns. Replaces the 40000-block
// version whose per-block 36.8 KB Wl1 re-read cost ~1.5 GB of L2 traffic.
__global__ __launch_bounds__(256) void k_final_mfma(
    const float* __restrict__ h, const float* __restrict__ ea3,
    const int* __restrict__ idx3, const u16* __restrict__ Wp1,
    const float* __restrict__ bl1, const float* __restrict__ Wl2,
    const float* __restrict__ bl2, float* __restrict__ out, int E3) {
  __shared__ __align__(16) u16 sF[64 * 104];
  int e0 = blockIdx.x * 64;
  int tid = threadIdx.x;
  {
    int er = tid >> 2;        // edge 0..63
    int part = tid & 3;       // k-quarter (24 each)
    int ge = e0 + er;
    int gc = (ge < E3) ? ge : E3 - 1;
    int a = idx3[gc], b = idx3[E3 + gc];
    for (int kk = part * 24; kk < part * 24 + 24; ++kk) {
      float v;
      if (kk < 64) v = 0.5f * (h[(size_t)a * 64 + kk] + h[(size_t)b * 64 + kk]);
      else if (kk < 72) v = ea3[(size_t)gc * 8 + (kk - 64)];
      else v = 0.0f;
      sF[er * 104 + kk] = f2bf(v);
    }
  }
  __syncthreads();
  int wave = tid >> 6, lane = tid & 63;
  int c = lane & 15, q = lane >> 4;
  float4v acc[8];
#pragma unroll
  for (int nt = 0; nt < 8; ++nt) acc[nt] = (float4v){0.f, 0.f, 0.f, 0.f};
#pragma unroll
  for (int ks = 0; ks < 3; ++ks) {
    short8v af = *(const short8v*)(&sF[(wave * 16 + c) * 104 + ks * 32 + q * 8]);
#pragma unroll
    for (int nt = 0; nt < 8; ++nt) {
      short8v bf = *(const short8v*)(Wp1 + ((size_t)(ks * 8 + nt) * 64 + lane) * 8);
      acc[nt] = __builtin_amdgcn_mfma_f32_16x16x32_bf16(af, bf, acc[nt], 0, 0, 0);
    }
  }
  float v[4] = {0.f, 0.f, 0.f, 0.f};
#pragma unroll
  for (int nt = 0; nt < 8; ++nt) {
    int n = nt * 16 + c;
    float b1 = bl1[n];
    float w2 = Wl2[n];
#pragma unroll
    for (int r = 0; r < 4; ++r) v[r] += fmaxf(acc[nt][r] + b1, 0.0f) * w2;
  }
#pragma unroll
  for (int off = 1; off < 16; off <<= 1) {
#pragma unroll
    for (int r = 0; r < 4; ++r) v[r] += __shfl_xor(v[r], off);
  }
  if (c == 0) {
    float b2v = bl2[0];
#pragma unroll
    for (int r = 0; r < 4; ++r) {
      int e = e0 + wave * 16 + q * 4 + r;
      if (e < E3) out[e] = v[r] + b2v;
    }
  }
}

extern "C" void kernel_launch(void* const* d_in, const int* in_sizes, int n_in,
                              void* d_out, int out_size, void* d_ws, size_t ws_size,
                              hipStream_t stream) {
  const float* x          = (const float*)d_in[0];
  const float* edge_attr  = (const float*)d_in[1];
  const float* edge_attr3 = (const float*)d_in[2];
  const int*   edge_index = (const int*)d_in[3];
  const int*   edge_index3= (const int*)d_in[4];
  const float* W_node = (const float*)d_in[5];
  const float* b_node = (const float*)d_in[6];
  const float* W_ea   = (const float*)d_in[7];
  const float* b_ea   = (const float*)d_in[8];
  const float* W_e1   = (const float*)d_in[9];
  const float* b_e1   = (const float*)d_in[10];
  const float* W_e2   = (const float*)d_in[11];
  const float* b_e2   = (const float*)d_in[12];
  const float* conv_bias = (const float*)d_in[13];
  const float* W_ih   = (const float*)d_in[14];
  const float* b_ih   = (const float*)d_in[15];
  const float* W_hh   = (const float*)d_in[16];
  const float* b_hh   = (const float*)d_in[17];
  const float* W_l1   = (const float*)d_in[18];
  const float* b_l1   = (const float*)d_in[19];
  const float* W_l2   = (const float*)d_in[20];
  const float* b_l2   = (const float*)d_in[21];

  int N  = in_sizes[0] / 8;
  int E  = in_sizes[1] / 19;
  int E3 = in_sizes[2] / 8;

  char* p = (char*)d_ws;
  auto carve = [&](size_t bytes) -> void* {
    char* q = p;
    p += (bytes + 255) & ~(size_t)255;
    return (void*)q;
  };
  float* hA   = (float*)carve((size_t)N * 64 * 4);
  float* hB   = (float*)carve((size_t)N * 64 * 4);
  float* agg  = (float*)carve((size_t)N * 64 * 4);
  int*   cnt  = (int*)carve((size_t)N * 4);
  u16*   Ahi  = (u16*)carve((size_t)E * 128 * 2);
  u16*   Bph  = (u16*)carve((size_t)128 * 4096 * 2);
  u16*   WpI  = (u16*)carve(12288 * 2);
  u16*   WpH  = (u16*)carve(12288 * 2);
  u16*   Wp1  = (u16*)carve(12288 * 2);

  const int* src = edge_index;
  const int* dst = edge_index + E;

  k_zero_i<<<(N + 255) / 256, 256, 0, stream>>>(cnt, N);
  k_cnt<<<(E + 255) / 256, 256, 0, stream>>>(dst, cnt, E);
  k_node<<<((size_t)N * 64 + 255) / 256, 256, 0, stream>>>(x, W_node, b_node, hA, N);
  k_edge_mlp<<<(E + 1) / 2, 256, 0, stream>>>(edge_attr, W_ea, b_ea, W_e1, b_e1, Ahi, E);
  k_pack_b<<<(128 * 4096 + 255) / 256, 256, 0, stream>>>(W_e2, Bph);
  k_prep_wtf<<<(2 * 12288 + 255) / 256, 256, 0, stream>>>(W_ih, W_hh, WpI, WpH);
  k_prep_wl1<<<(12288 + 255) / 256, 256, 0, stream>>>(W_l1, Wp1);
  k_zero_f<<<((size_t)N * 64 + 255) / 256, 256, 0, stream>>>(agg, N * 64);

  float* hcur = hA;
  float* hnxt = hB;
  dim3 gconv((E + 127) / 128, 2);
  int ngru = (N + 63) / 64;
  for (int it = 0; it < 3; ++it) {
    k_conv_fused<<<gconv, 256, 0, stream>>>(Ahi, Bph, b_e2, hcur, src, dst, agg, E);
    k_gru_mfma<<<ngru, 256, 0, stream>>>(agg, cnt, conv_bias, WpI, WpH,
                                         b_ih, b_hh, hcur, hnxt, N);
    float* tmp = hcur; hcur = hnxt; hnxt = tmp;
  }
  k_final_mfma<<<(E3 + 63) / 64, 256, 0, stream>>>(hcur, edge_attr3, edge_index3, Wp1,
                                                   b_l1, W_l2, b_l2, (float*)d_out, E3);
}